// Round 6
// baseline (1268.220 us; speedup 1.0000x reference)
//
#include <hip/hip_runtime.h>
#include <hip/hip_bf16.h>
#include <math.h>

// dims
#define MMX 64
#define NNX 128
#define DDX 64
#define RDX 128
#define TTX 96
#define LLX 512
#define PROWS 67    // padded rows: m in [-1, 65]
#define PCOLS 130   // padded cols: n in [-1, 128]

typedef short bfx8 __attribute__((ext_vector_type(8)));
typedef float floatx4 __attribute__((ext_vector_type(4)));

__device__ __forceinline__ float gelu(float v) {
  return 0.5f * v * (1.0f + erff(v * 0.70710678118654752f));
}

// ---------------------------------------------------------------------------
// prep: conv weight fp32 [CO][CI][4][3] -> bf16 [dd=dm*3+dn][co][ci]
// ---------------------------------------------------------------------------
__global__ __launch_bounds__(256) void castw_kernel(
    const float* __restrict__ w, __hip_bfloat16* __restrict__ o, int CO, int CI) {
  int i = blockIdx.x * 256 + threadIdx.x;      // CO*CI*12 total
  int ci = i % CI;
  int t = i / CI;
  int co = t % CO;
  int dd = t / CO;
  o[i] = __float2bfloat16(w[(size_t)(co * CI + ci) * 12 + dd]);
}

// ---------------------------------------------------------------------------
// prep: head weight fp32 [96][f=d*128+n] -> bf16 [96][fh=n*64+d]
// ---------------------------------------------------------------------------
__global__ __launch_bounds__(256) void headw_kernel(
    const float* __restrict__ hw, __hip_bfloat16* __restrict__ o) {
  int i = blockIdx.x * 256 + threadIdx.x;      // 96*8192 total
  int fh = i & 8191;
  int t = i >> 13;
  int d = fh & 63;
  int n = fh >> 6;
  o[i] = __float2bfloat16(hw[(size_t)t * 8192 + d * 128 + n]);
}

// ---------------------------------------------------------------------------
// embed: x [B*M, L] fp32 -> X [Bc*M, N, D] fp32 (k=8 stride=4, edge-pad right)
// ---------------------------------------------------------------------------
__global__ __launch_bounds__(256) void embed_kernel(
    const float* __restrict__ x, const float* __restrict__ w,
    const float* __restrict__ bias, float* __restrict__ xe, int bm_off) {
  int tid = blockIdx.x * 256 + threadIdx.x;
  int d  = tid & 63;
  int n  = (tid >> 6) & 127;
  int bm = tid >> 13;
  const float* xr = x + (size_t)(bm_off + bm) * LLX;
  float acc = bias[d];
  int base = n * 4;
#pragma unroll
  for (int p = 0; p < 8; ++p) {
    int i = base + p;
    if (i > LLX - 1) i = LLX - 1;
    acc += w[d * 8 + p] * xr[i];
  }
  xe[tid] = acc;
}

// ---------------------------------------------------------------------------
// depthwise conv over M (k=4, zero-pad 1/2): X fp32 [b,m,n,d] -> Yp bf16 padded
// Yp layout [b][PROWS][PCOLS][64], interior at [m+1][n+1]; halos pre-zeroed.
// ---------------------------------------------------------------------------
__global__ __launch_bounds__(256) void dw_kernel(
    const float* __restrict__ xe, const float* __restrict__ w,
    const float* __restrict__ bias, __hip_bfloat16* __restrict__ yp) {
  int tid = blockIdx.x * 256 + threadIdx.x;
  int d = tid & 63;
  int n = (tid >> 6) & 127;
  int m = (tid >> 13) & 63;
  int b = tid >> 19;
  int c = n * DDX + d;
  float acc = bias[c];
#pragma unroll
  for (int k = 0; k < 4; ++k) {
    int mm2 = m - 1 + k;
    if (mm2 >= 0 && mm2 < MMX)
      acc += w[c * 4 + k] * xe[((size_t)(b * MMX + mm2) * NNX + n) * DDX + d];
  }
  yp[(((size_t)b * PROWS + m + 1) * PCOLS + n + 1) * DDX + d] = __float2bfloat16(acc);
}

// ---------------------------------------------------------------------------
// All-global MFMA conv2d 4x3 (zero pad via halo buffers). No LDS, no barriers.
// Block = one (b, m): 128 px x COUT. 4 waves: (w>>1)=px half, (w&1)=co half.
// in padded [b][67][130][CIN]; wT [12][COUT][CIN]; A,B fragments loaded
// directly from global (16B contiguous), L1/L2-served.
// GELU: write Hp padded interior. else: X += (resid, fp32) and Xb (bf16 copy).
// ---------------------------------------------------------------------------
template <int CIN, int COUT, bool GELU>
__global__ __launch_bounds__(256) void conv_gmfma(
    const __hip_bfloat16* __restrict__ in,
    const __hip_bfloat16* __restrict__ wT,
    const float* __restrict__ bias,
    __hip_bfloat16* __restrict__ hout,   // padded [b][67][130][COUT]
    float* xio,                          // [b][64][128][COUT]
    __hip_bfloat16* __restrict__ xb) {   // [b][64][128][COUT] bf16
  constexpr int PT = 4;
  constexpr int CT = COUT / 32;          // conv1: 4, conv2: 2
  const int m = blockIdx.x & 63;
  const int b = blockIdx.x >> 6;
  const int lane = threadIdx.x & 63;
  const int w = threadIdx.x >> 6;
  const int wp0 = (w >> 1) * 64;
  const int wc0 = (w & 1) * (COUT / 2);
  const int l15 = lane & 15;
  const int quad = lane >> 4;

  floatx4 acc[PT][CT];
#pragma unroll
  for (int i = 0; i < PT; ++i)
#pragma unroll
    for (int j = 0; j < CT; ++j) acc[i][j] = (floatx4)0.f;

  // padded row mm = (m-1+dm)+1 = m+dm; padded col nn = px+dn (always in range)
  const __hip_bfloat16* arow0 = in + ((size_t)b * PROWS + m) * PCOLS * CIN;
  for (int dm = 0; dm < 4; ++dm) {
    const __hip_bfloat16* ar = arow0 + (size_t)dm * PCOLS * CIN;
#pragma unroll
    for (int dn = 0; dn < 3; ++dn) {
      const __hip_bfloat16* wp = wT + (size_t)(dm * 3 + dn) * COUT * CIN;
#pragma unroll
      for (int kc = 0; kc < CIN / 32; ++kc) {
        const int kb = kc * 32 + quad * 8;
        bfx8 a[PT], bv[CT];
#pragma unroll
        for (int i = 0; i < PT; ++i)
          a[i] = *(const bfx8*)(ar + (size_t)(wp0 + 16 * i + l15 + dn) * CIN + kb);
#pragma unroll
        for (int j = 0; j < CT; ++j)
          bv[j] = *(const bfx8*)(wp + (size_t)(wc0 + 16 * j + l15) * CIN + kb);
#pragma unroll
        for (int i = 0; i < PT; ++i)
#pragma unroll
          for (int j = 0; j < CT; ++j)
            acc[i][j] = __builtin_amdgcn_mfma_f32_16x16x32_bf16(
                a[i], bv[j], acc[i][j], 0, 0, 0);
      }
    }
  }

  // D: row(pixel)=quad*4+r, col(co)=l15
#pragma unroll
  for (int j = 0; j < CT; ++j) {
    int co = wc0 + 16 * j + l15;
    float bvs = bias[co];
#pragma unroll
    for (int i = 0; i < PT; ++i) {
#pragma unroll
      for (int r = 0; r < 4; ++r) {
        int p = wp0 + 16 * i + quad * 4 + r;
        float v = acc[i][j][r] + bvs;
        if (GELU) {
          size_t idx = (((size_t)b * PROWS + m + 1) * PCOLS + p + 1) * COUT + co;
          hout[idx] = __float2bfloat16(gelu(v));
        } else {
          size_t idx = (((size_t)b * MMX + m) * NNX + p) * COUT + co;
          float r2 = v + xio[idx];
          xio[idx] = r2;
          xb[idx] = __float2bfloat16(r2);
        }
      }
    }
  }
}

// ---------------------------------------------------------------------------
// head split-K: P[ks][bm][t] = sum_{k in slice} Xb[bm][k] * hwT[t][k]
// grid = Bc * 8; block = 64 bm x 96 t x K=1024. 4 waves = 16 bm each.
// ---------------------------------------------------------------------------
__global__ __launch_bounds__(256) void head_split(
    const __hip_bfloat16* __restrict__ xb,   // [nbm][8192]
    const __hip_bfloat16* __restrict__ hwT,  // [96][8192]
    float* __restrict__ P, int nbm) {        // [8][nbm][96]
  const int ks = blockIdx.x & 7;
  const int bm0 = (blockIdx.x >> 3) * 64;
  const int lane = threadIdx.x & 63;
  const int w = threadIdx.x >> 6;
  const int l15 = lane & 15;
  const int quad = lane >> 4;
  const int bmw = bm0 + w * 16;

  floatx4 acc[6];
#pragma unroll
  for (int j = 0; j < 6; ++j) acc[j] = (floatx4)0.f;

  const int k0 = ks * 1024;
  const __hip_bfloat16* abase = xb + (size_t)(bmw + l15) * 8192 + k0;
  const __hip_bfloat16* bbase = hwT + (size_t)l15 * 8192 + k0;
#pragma unroll 4
  for (int kc = 0; kc < 32; ++kc) {
    const int kb = kc * 32 + quad * 8;
    bfx8 a = *(const bfx8*)(abase + kb);
#pragma unroll
    for (int j = 0; j < 6; ++j) {
      bfx8 bv = *(const bfx8*)(bbase + (size_t)(16 * j) * 8192 + kb);
      acc[j] = __builtin_amdgcn_mfma_f32_16x16x32_bf16(a, bv, acc[j], 0, 0, 0);
    }
  }
#pragma unroll
  for (int j = 0; j < 6; ++j) {
    int t = 16 * j + l15;
#pragma unroll
    for (int r = 0; r < 4; ++r) {
      int bm = bmw + quad * 4 + r;
      P[((size_t)ks * nbm + bm) * TTX + t] = acc[j][r];
    }
  }
}

__global__ __launch_bounds__(256) void head_reduce(
    const float* __restrict__ P, const float* __restrict__ hb,
    float* __restrict__ out, int nbm, int bm_off) {
  int i = blockIdx.x * 256 + threadIdx.x;    // nbm*96
  int t = i % TTX;
  int bm = i / TTX;
  float s = hb[t];
#pragma unroll
  for (int ks = 0; ks < 8; ++ks) s += P[((size_t)ks * nbm + bm) * TTX + t];
  out[(size_t)(bm_off + bm) * TTX + t] = s;
}

// ---------------------------------------------------------------------------
extern "C" void kernel_launch(void* const* d_in, const int* in_sizes, int n_in,
                              void* d_out, int out_size, void* d_ws, size_t ws_size,
                              hipStream_t stream) {
  const float* x      = (const float*)d_in[0];
  const float* emb_w  = (const float*)d_in[1];
  const float* emb_b  = (const float*)d_in[2];
  const float* head_w = (const float*)d_in[3];
  const float* head_b = (const float*)d_in[4];
  const float* dw_w1  = (const float*)d_in[5];
  const float* dw_b1  = (const float*)d_in[6];
  const float* f11_w  = (const float*)d_in[7];
  const float* f11_b  = (const float*)d_in[8];
  const float* f12_w  = (const float*)d_in[9];
  const float* f12_b  = (const float*)d_in[10];
  const float* dw_w2  = (const float*)d_in[11];
  const float* dw_b2  = (const float*)d_in[12];
  const float* f21_w  = (const float*)d_in[13];
  const float* f21_b  = (const float*)d_in[14];
  const float* f22_w  = (const float*)d_in[15];
  const float* f22_b  = (const float*)d_in[16];

  // fixed: 4 conv wT (98304 bf16 each) + hwT (786432 bf16)
  const size_t WEL = 98304, HWEL = 786432;
  __hip_bfloat16* wt11 = (__hip_bfloat16*)d_ws;
  __hip_bfloat16* wt12 = wt11 + WEL;
  __hip_bfloat16* wt21 = wt12 + WEL;
  __hip_bfloat16* wt22 = wt21 + WEL;
  __hip_bfloat16* hwT  = wt22 + WEL;
  char* dyn = (char*)(hwT + HWEL);
  const size_t fixed_bytes = (4 * WEL + HWEL) * 2;

  // per-b bytes: Yp 1,114,880 + Hp 2,229,760 + X 2,097,152 + Xb 1,048,576 + P 196,608
  const size_t YP_B = (size_t)PROWS * PCOLS * DDX * 2;    // 1,114,880
  const size_t HP_B = (size_t)PROWS * PCOLS * RDX * 2;    // 2,229,760
  const size_t X_B  = (size_t)MMX * NNX * DDX * 4;        // 2,097,152
  const size_t XB_B = (size_t)MMX * NNX * DDX * 2;        // 1,048,576
  const size_t P_B  = (size_t)8 * MMX * TTX * 4;          //   196,608
  const size_t PER_B = YP_B + HP_B + X_B + XB_B + P_B;
  int Bc = 32;
  while (Bc > 1 && fixed_bytes + (size_t)Bc * PER_B > ws_size) Bc >>= 1;

  __hip_bfloat16* Yp = (__hip_bfloat16*)dyn;
  __hip_bfloat16* Hp = (__hip_bfloat16*)(dyn + (size_t)Bc * YP_B);
  float* X  = (float*)(dyn + (size_t)Bc * (YP_B + HP_B));
  __hip_bfloat16* Xb = (__hip_bfloat16*)(dyn + (size_t)Bc * (YP_B + HP_B + X_B));
  float* P  = (float*)(dyn + (size_t)Bc * (YP_B + HP_B + X_B + XB_B));
  const int nbm = Bc * MMX;

  // prep (once per launch)
  castw_kernel<<<384, 256, 0, stream>>>(f11_w, wt11, RDX, DDX);
  castw_kernel<<<384, 256, 0, stream>>>(f12_w, wt12, DDX, RDX);
  castw_kernel<<<384, 256, 0, stream>>>(f21_w, wt21, RDX, DDX);
  castw_kernel<<<384, 256, 0, stream>>>(f22_w, wt22, DDX, RDX);
  headw_kernel<<<3072, 256, 0, stream>>>(head_w, hwT);
  // zero the padded halo buffers (halos persist; interiors rewritten per chunk)
  hipMemsetAsync(Yp, 0, (size_t)Bc * (YP_B + HP_B), stream);

  for (int b0 = 0; b0 < 32; b0 += Bc) {
    int bm_off = b0 * MMX;
    embed_kernel<<<Bc * 2048, 256, 0, stream>>>(x, emb_w, emb_b, X, bm_off);

    for (int l = 0; l < 2; ++l) {
      const float* dwW = l ? dw_w2 : dw_w1;
      const float* dwB = l ? dw_b2 : dw_b1;
      const __hip_bfloat16* w1 = l ? wt21 : wt11;
      const float* b1 = l ? f21_b : f11_b;
      const __hip_bfloat16* w2 = l ? wt22 : wt12;
      const float* b2 = l ? f22_b : f12_b;

      dw_kernel<<<Bc * 2048, 256, 0, stream>>>(X, dwW, dwB, Yp);
      conv_gmfma<DDX, RDX, true>
          <<<Bc * MMX, 256, 0, stream>>>(Yp, w1, b1, Hp, nullptr, nullptr);
      conv_gmfma<RDX, DDX, false>
          <<<Bc * MMX, 256, 0, stream>>>(Hp, w2, b2, nullptr, X, Xb);
    }

    head_split<<<Bc * 8, 256, 0, stream>>>(Xb, hwT, P, nbm);
    head_reduce<<<Bc * 24, 256, 0, stream>>>(P, head_b, (float*)d_out, nbm, bm_off);
  }
}

// Round 7
// 929.376 us; speedup vs baseline: 1.3646x; 1.3646x over previous
//
#include <hip/hip_runtime.h>
#include <hip/hip_bf16.h>
#include <math.h>

// dims
#define MMX 64
#define NNX 128
#define DDX 64
#define RDX 128
#define TTX 96
#define LLX 512
#define PROWS 67    // padded rows: m in [-1, 65]
#define PCOLS 130   // padded cols: n in [-1, 128]

typedef short bfx8 __attribute__((ext_vector_type(8)));
typedef float floatx4 __attribute__((ext_vector_type(4)));

__device__ __forceinline__ float gelu(float v) {
  return 0.5f * v * (1.0f + erff(v * 0.70710678118654752f));
}

// ---------------------------------------------------------------------------
// prep: conv weight fp32 [CO][CI][4][3] -> bf16 [dd=dm*3+dn][co][ci]
// ---------------------------------------------------------------------------
__global__ __launch_bounds__(256) void castw_kernel(
    const float* __restrict__ w, __hip_bfloat16* __restrict__ o, int CO, int CI) {
  int i = blockIdx.x * 256 + threadIdx.x;      // CO*CI*12 total
  int ci = i % CI;
  int t = i / CI;
  int co = t % CO;
  int dd = t / CO;
  o[i] = __float2bfloat16(w[(size_t)(co * CI + ci) * 12 + dd]);
}

// ---------------------------------------------------------------------------
// prep: head weight fp32 [96][f=d*128+n] -> bf16 [96][fh=n*64+d]
// ---------------------------------------------------------------------------
__global__ __launch_bounds__(256) void headw_kernel(
    const float* __restrict__ hw, __hip_bfloat16* __restrict__ o) {
  int i = blockIdx.x * 256 + threadIdx.x;      // 96*8192 total
  int fh = i & 8191;
  int t = i >> 13;
  int d = fh & 63;
  int n = fh >> 6;
  o[i] = __float2bfloat16(hw[(size_t)t * 8192 + d * 128 + n]);
}

// ---------------------------------------------------------------------------
// embed: x [B*M, L] fp32 -> X [Bc*M, N, D] fp32 (k=8 stride=4, edge-pad right)
// ---------------------------------------------------------------------------
__global__ __launch_bounds__(256) void embed_kernel(
    const float* __restrict__ x, const float* __restrict__ w,
    const float* __restrict__ bias, float* __restrict__ xe, int bm_off) {
  int tid = blockIdx.x * 256 + threadIdx.x;
  int d  = tid & 63;
  int n  = (tid >> 6) & 127;
  int bm = tid >> 13;
  const float* xr = x + (size_t)(bm_off + bm) * LLX;
  float acc = bias[d];
  int base = n * 4;
#pragma unroll
  for (int p = 0; p < 8; ++p) {
    int i = base + p;
    if (i > LLX - 1) i = LLX - 1;
    acc += w[d * 8 + p] * xr[i];
  }
  xe[tid] = acc;
}

// ---------------------------------------------------------------------------
// depthwise conv over M (k=4, zero-pad 1/2): X fp32 [b,m,n,d] -> Yp bf16 padded
// Yp layout [b][PROWS][PCOLS][64], interior at [m+1][n+1]; halos pre-zeroed.
// ---------------------------------------------------------------------------
__global__ __launch_bounds__(256) void dw_kernel(
    const float* __restrict__ xe, const float* __restrict__ w,
    const float* __restrict__ bias, __hip_bfloat16* __restrict__ yp) {
  int tid = blockIdx.x * 256 + threadIdx.x;
  int d = tid & 63;
  int n = (tid >> 6) & 127;
  int m = (tid >> 13) & 63;
  int b = tid >> 19;
  int c = n * DDX + d;
  float acc = bias[c];
#pragma unroll
  for (int k = 0; k < 4; ++k) {
    int mm2 = m - 1 + k;
    if (mm2 >= 0 && mm2 < MMX)
      acc += w[c * 4 + k] * xe[((size_t)(b * MMX + mm2) * NNX + n) * DDX + d];
  }
  yp[(((size_t)b * PROWS + m + 1) * PCOLS + n + 1) * DDX + d] = __float2bfloat16(acc);
}

// ---------------------------------------------------------------------------
// MFMA conv2d 4x3, m97-style: A (pixel row) staged in LDS per dm, weights in
// VGPRs (12 bfx8/wave/dm), coalesced LDS-transposed epilogue.
// Block = one (b,m): 128 px x COUT. 4 waves: each all 128 px x COUT/4 co.
// in padded [b][67][130][CIN]; wT [12][COUT][CIN].
// GELU: write Hp padded interior (bf16). else: X += resid (fp32) and Xb bf16.
// ---------------------------------------------------------------------------
template <int CIN, int COUT, bool GELU>
__global__ __launch_bounds__(256) void conv_lds(
    const __hip_bfloat16* __restrict__ in,
    const __hip_bfloat16* __restrict__ wT,
    const float* __restrict__ bias,
    __hip_bfloat16* __restrict__ hout,   // padded [b][67][130][COUT]
    float* xio,                          // [b][64][128][COUT] fp32
    __hip_bfloat16* __restrict__ xb) {   // [b][64][128][COUT] bf16
  constexpr int ASTR = CIN + 8;          // LDS row stride (2-way max aliasing)
  constexpr int KC = CIN / 32;           // k-chunks per (dm,dn)
  constexpr int CT = COUT / 64;          // 16-co tiles per wave
  constexpr int PT = 8;                  // 16-px tiles per wave (all 128)
  __shared__ short smem[130 * ASTR];     // conv1 18.7 KB, conv2 35.4 KB

  const int m = blockIdx.x & 63;
  const int b = blockIdx.x >> 6;
  const int tid = threadIdx.x;
  const int lane = tid & 63;
  const int w = tid >> 6;
  const int wc0 = w * (COUT / 4);
  const int l15 = lane & 15;
  const int quad = lane >> 4;

  floatx4 acc[PT][CT];
#pragma unroll
  for (int i = 0; i < PT; ++i)
#pragma unroll
    for (int j = 0; j < CT; ++j) acc[i][j] = (floatx4)0.f;

#pragma unroll 1
  for (int dm = 0; dm < 4; ++dm) {
    // B fragments -> VGPRs (L2-hot; issued before barrier to overlap staging)
    bfx8 Bf[3][KC][CT];
    const __hip_bfloat16* wbase = wT + (size_t)dm * 3 * COUT * CIN;
#pragma unroll
    for (int dn = 0; dn < 3; ++dn)
#pragma unroll
      for (int kc = 0; kc < KC; ++kc)
#pragma unroll
        for (int j = 0; j < CT; ++j)
          Bf[dn][kc][j] = *(const bfx8*)(
              wbase + ((size_t)dn * COUT + wc0 + 16 * j + l15) * CIN +
              kc * 32 + quad * 8);

    __syncthreads();  // prior K-step smem reads done before restage
    {   // stage padded input row (m+dm): 130 cols x CIN, contiguous global
      const uint4* src = (const uint4*)(
          in + ((size_t)b * PROWS + m + dm) * PCOLS * CIN);
      constexpr int TOTCH = 130 * CIN / 8;
      for (int idx = tid; idx < TOTCH; idx += 256) {
        int col = idx / (CIN / 8), cg = idx % (CIN / 8);
        uint4 v = src[idx];
        *(uint4*)&smem[col * ASTR + cg * 8] = v;
      }
    }
    __syncthreads();

#pragma unroll
    for (int dn = 0; dn < 3; ++dn) {
#pragma unroll
      for (int kc = 0; kc < KC; ++kc) {
        const int kb = kc * 32 + quad * 8;
        bfx8 a[PT];
#pragma unroll
        for (int i = 0; i < PT; ++i)
          a[i] = *(const bfx8*)&smem[(16 * i + l15 + dn) * ASTR + kb];
#pragma unroll
        for (int j = 0; j < CT; ++j)
#pragma unroll
          for (int i = 0; i < PT; ++i)
            acc[i][j] = __builtin_amdgcn_mfma_f32_16x16x32_bf16(
                a[i], Bf[dn][kc][j], acc[i][j], 0, 0, 0);
      }
    }
  }

  // bias
  float bs[CT];
#pragma unroll
  for (int j = 0; j < CT; ++j) bs[j] = bias[wc0 + 16 * j + l15];

  // epilogue: LDS transpose per 64-px half -> coalesced wide stores
  // D layout: row(pixel)=quad*4+r within tile i, col(co)=l15
  __syncthreads();  // all K-loop smem reads done before reuse
#pragma unroll 1
  for (int h = 0; h < 2; ++h) {
    if (GELU) {
      constexpr int STR2 = COUT + 8;     // shorts
      short* t2 = smem;
#pragma unroll
      for (int j = 0; j < CT; ++j)
#pragma unroll
        for (int ii = 0; ii < 4; ++ii)
#pragma unroll
          for (int r = 0; r < 4; ++r) {
            int i = h * 4 + ii;
            int pl = 16 * ii + quad * 4 + r;
            __hip_bfloat16 bv = __float2bfloat16(gelu(acc[i][j][r] + bs[j]));
            t2[pl * STR2 + wc0 + 16 * j + l15] = *(short*)&bv;
          }
      __syncthreads();
      constexpr int CHUNKS = 64 * COUT / 8;   // 1024
      size_t gbase = (((size_t)b * PROWS + m + 1) * PCOLS + 1 + h * 64) * COUT;
      for (int idx = tid; idx < CHUNKS; idx += 256) {
        int px = idx / (COUT / 8), cg = idx % (COUT / 8);
        uint4 v = *(uint4*)&t2[px * STR2 + cg * 8];
        *(uint4*)(hout + gbase + (size_t)px * COUT + cg * 8) = v;
      }
      __syncthreads();
    } else {
      constexpr int STRF = COUT + 4;     // floats
      float* tf = (float*)smem;
#pragma unroll
      for (int j = 0; j < CT; ++j)
#pragma unroll
        for (int ii = 0; ii < 4; ++ii)
#pragma unroll
          for (int r = 0; r < 4; ++r) {
            int i = h * 4 + ii;
            int pl = 16 * ii + quad * 4 + r;
            tf[pl * STRF + wc0 + 16 * j + l15] = acc[i][j][r] + bs[j];
          }
      __syncthreads();
      constexpr int CHUNKS = 64 * COUT / 4;   // 1024
      size_t gbase = (((size_t)b * MMX + m) * NNX + h * 64) * COUT;
      for (int idx = tid; idx < CHUNKS; idx += 256) {
        int px = idx / (COUT / 4), cg = idx % (COUT / 4);
        float4 a4 = *(float4*)&tf[px * STRF + cg * 4];
        size_t gx = gbase + (size_t)px * COUT + cg * 4;
        float4 xv = *(float4*)(xio + gx);
        float4 rr = make_float4(a4.x + xv.x, a4.y + xv.y, a4.z + xv.z, a4.w + xv.w);
        *(float4*)(xio + gx) = rr;
        __hip_bfloat16 o0 = __float2bfloat16(rr.x), o1 = __float2bfloat16(rr.y);
        __hip_bfloat16 o2 = __float2bfloat16(rr.z), o3 = __float2bfloat16(rr.w);
        ushort4 ov = make_ushort4(*(unsigned short*)&o0, *(unsigned short*)&o1,
                                  *(unsigned short*)&o2, *(unsigned short*)&o3);
        *(ushort4*)(xb + gx) = ov;
      }
      __syncthreads();
    }
  }
}

// ---------------------------------------------------------------------------
// head split-K: P[ks][bm][t] = sum_{k in slice} Xb[bm][k] * hwT[t][k]
// grid = Bc * 8; block = 64 bm x 96 t x K=1024. 4 waves = 16 bm each.
// ---------------------------------------------------------------------------
__global__ __launch_bounds__(256) void head_split(
    const __hip_bfloat16* __restrict__ xb,   // [nbm][8192]
    const __hip_bfloat16* __restrict__ hwT,  // [96][8192]
    float* __restrict__ P, int nbm) {        // [8][nbm][96]
  const int ks = blockIdx.x & 7;
  const int bm0 = (blockIdx.x >> 3) * 64;
  const int lane = threadIdx.x & 63;
  const int w = threadIdx.x >> 6;
  const int l15 = lane & 15;
  const int quad = lane >> 4;
  const int bmw = bm0 + w * 16;

  floatx4 acc[6];
#pragma unroll
  for (int j = 0; j < 6; ++j) acc[j] = (floatx4)0.f;

  const int k0 = ks * 1024;
  const __hip_bfloat16* abase = xb + (size_t)(bmw + l15) * 8192 + k0;
  const __hip_bfloat16* bbase = hwT + (size_t)l15 * 8192 + k0;
#pragma unroll 4
  for (int kc = 0; kc < 32; ++kc) {
    const int kb = kc * 32 + quad * 8;
    bfx8 a = *(const bfx8*)(abase + kb);
#pragma unroll
    for (int j = 0; j < 6; ++j) {
      bfx8 bv = *(const bfx8*)(bbase + (size_t)(16 * j) * 8192 + kb);
      acc[j] = __builtin_amdgcn_mfma_f32_16x16x32_bf16(a, bv, acc[j], 0, 0, 0);
    }
  }
#pragma unroll
  for (int j = 0; j < 6; ++j) {
    int t = 16 * j + l15;
#pragma unroll
    for (int r = 0; r < 4; ++r) {
      int bm = bmw + quad * 4 + r;
      P[((size_t)ks * nbm + bm) * TTX + t] = acc[j][r];
    }
  }
}

__global__ __launch_bounds__(256) void head_reduce(
    const float* __restrict__ P, const float* __restrict__ hb,
    float* __restrict__ out, int nbm, int bm_off) {
  int i = blockIdx.x * 256 + threadIdx.x;    // nbm*96
  int t = i % TTX;
  int bm = i / TTX;
  float s = hb[t];
#pragma unroll
  for (int ks = 0; ks < 8; ++ks) s += P[((size_t)ks * nbm + bm) * TTX + t];
  out[(size_t)(bm_off + bm) * TTX + t] = s;
}

// ---------------------------------------------------------------------------
extern "C" void kernel_launch(void* const* d_in, const int* in_sizes, int n_in,
                              void* d_out, int out_size, void* d_ws, size_t ws_size,
                              hipStream_t stream) {
  const float* x      = (const float*)d_in[0];
  const float* emb_w  = (const float*)d_in[1];
  const float* emb_b  = (const float*)d_in[2];
  const float* head_w = (const float*)d_in[3];
  const float* head_b = (const float*)d_in[4];
  const float* dw_w1  = (const float*)d_in[5];
  const float* dw_b1  = (const float*)d_in[6];
  const float* f11_w  = (const float*)d_in[7];
  const float* f11_b  = (const float*)d_in[8];
  const float* f12_w  = (const float*)d_in[9];
  const float* f12_b  = (const float*)d_in[10];
  const float* dw_w2  = (const float*)d_in[11];
  const float* dw_b2  = (const float*)d_in[12];
  const float* f21_w  = (const float*)d_in[13];
  const float* f21_b  = (const float*)d_in[14];
  const float* f22_w  = (const float*)d_in[15];
  const float* f22_b  = (const float*)d_in[16];

  // fixed: 4 conv wT (98304 bf16 each) + hwT (786432 bf16)
  const size_t WEL = 98304, HWEL = 786432;
  __hip_bfloat16* wt11 = (__hip_bfloat16*)d_ws;
  __hip_bfloat16* wt12 = wt11 + WEL;
  __hip_bfloat16* wt21 = wt12 + WEL;
  __hip_bfloat16* wt22 = wt21 + WEL;
  __hip_bfloat16* hwT  = wt22 + WEL;
  char* dyn = (char*)(hwT + HWEL);
  const size_t fixed_bytes = (4 * WEL + HWEL) * 2;

  const size_t YP_B = (size_t)PROWS * PCOLS * DDX * 2;    // 1,114,880
  const size_t HP_B = (size_t)PROWS * PCOLS * RDX * 2;    // 2,229,760
  const size_t X_B  = (size_t)MMX * NNX * DDX * 4;        // 2,097,152
  const size_t XB_B = (size_t)MMX * NNX * DDX * 2;        // 1,048,576
  const size_t P_B  = (size_t)8 * MMX * TTX * 4;          //   196,608
  const size_t PER_B = YP_B + HP_B + X_B + XB_B + P_B;
  int Bc = 32;
  while (Bc > 1 && fixed_bytes + (size_t)Bc * PER_B > ws_size) Bc >>= 1;

  __hip_bfloat16* Yp = (__hip_bfloat16*)dyn;
  __hip_bfloat16* Hp = (__hip_bfloat16*)(dyn + (size_t)Bc * YP_B);
  float* X  = (float*)(dyn + (size_t)Bc * (YP_B + HP_B));
  __hip_bfloat16* Xb = (__hip_bfloat16*)(dyn + (size_t)Bc * (YP_B + HP_B + X_B));
  float* P  = (float*)(dyn + (size_t)Bc * (YP_B + HP_B + X_B + XB_B));
  const int nbm = Bc * MMX;

  // prep (once per launch)
  castw_kernel<<<384, 256, 0, stream>>>(f11_w, wt11, RDX, DDX);
  castw_kernel<<<384, 256, 0, stream>>>(f12_w, wt12, DDX, RDX);
  castw_kernel<<<384, 256, 0, stream>>>(f21_w, wt21, RDX, DDX);
  castw_kernel<<<384, 256, 0, stream>>>(f22_w, wt22, DDX, RDX);
  headw_kernel<<<3072, 256, 0, stream>>>(head_w, hwT);
  // zero padded halo buffers (ws is re-poisoned before every timed launch)
  hipMemsetAsync(Yp, 0, (size_t)Bc * (YP_B + HP_B), stream);

  for (int b0 = 0; b0 < 32; b0 += Bc) {
    int bm_off = b0 * MMX;
    embed_kernel<<<Bc * 2048, 256, 0, stream>>>(x, emb_w, emb_b, X, bm_off);

    for (int l = 0; l < 2; ++l) {
      const float* dwW = l ? dw_w2 : dw_w1;
      const float* dwB = l ? dw_b2 : dw_b1;
      const __hip_bfloat16* w1 = l ? wt21 : wt11;
      const float* b1 = l ? f21_b : f11_b;
      const __hip_bfloat16* w2 = l ? wt22 : wt12;
      const float* b2 = l ? f22_b : f12_b;

      dw_kernel<<<Bc * 2048, 256, 0, stream>>>(X, dwW, dwB, Yp);
      conv_lds<DDX, RDX, true>
          <<<Bc * MMX, 256, 0, stream>>>(Yp, w1, b1, Hp, nullptr, nullptr);
      conv_lds<RDX, DDX, false>
          <<<Bc * MMX, 256, 0, stream>>>(Hp, w2, b2, nullptr, X, Xb);
    }

    head_split<<<Bc * 8, 256, 0, stream>>>(Xb, hwT, P, nbm);
    head_reduce<<<Bc * 24, 256, 0, stream>>>(P, head_b, (float*)d_out, nbm, bm_off);
  }
}